// Round 1
// baseline (1793.914 us; speedup 1.0000x reference)
//
#include <hip/hip_runtime.h>
#include <math.h>

#define D 256

typedef short short8 __attribute__((ext_vector_type(8)));
typedef float f32x4 __attribute__((ext_vector_type(4)));

__device__ __forceinline__ float bf2f(unsigned int h) {
  return __uint_as_float(h << 16);
}
__device__ __forceinline__ unsigned short f2bf(float f) {
  unsigned int u = __float_as_uint(f);
  u += 0x7fffu + ((u >> 16) & 1u);
  return (unsigned short)(u >> 16);
}

// ---------------- degree count ----------------
__global__ __launch_bounds__(256) void k_count(const int* __restrict__ row,
                                               int* __restrict__ cnt, int E) {
  int i = blockIdx.x * 256 + threadIdx.x;
  if (i < E) atomicAdd(&cnt[row[i]], 1);
}

// ---------------- exclusive scan + dinv (single block, 1024 thr) ----------------
__global__ __launch_bounds__(1024) void k_scan(const int* __restrict__ cnt,
                                               int* __restrict__ offs,
                                               float* __restrict__ dinv, int n) {
  __shared__ int sw[16];
  __shared__ int sbase;
  int tid = threadIdx.x;
  int lane = tid & 63;
  int wid = tid >> 6;
  if (tid == 0) sbase = 0;
  __syncthreads();
  for (int base = 0; base < n; base += 1024) {
    int i = base + tid;
    int v = (i < n) ? cnt[i] : 0;
    int x = v;
#pragma unroll
    for (int d2 = 1; d2 < 64; d2 <<= 1) {
      int y = __shfl_up(x, d2, 64);
      if (lane >= d2) x += y;
    }
    if (lane == 63) sw[wid] = x;
    __syncthreads();
    int woff = sbase;
    for (int w2 = 0; w2 < wid; ++w2) woff += sw[w2];
    int incl = woff + x;
    if (i < n) {
      offs[i] = incl - v;              // exclusive prefix
      dinv[i] = rsqrtf((float)(v + 1)); // +1 self loop; deg>=1 always
    }
    __syncthreads();
    if (tid == 1023) sbase = incl;
    __syncthreads();
  }
  if (tid == 0) offs[n] = sbase;
}

// ---------------- CSR scatter + per-edge norm ----------------
__global__ __launch_bounds__(256) void k_scatter(const int* __restrict__ row,
                                                 const int* __restrict__ col,
                                                 const int* __restrict__ offs,
                                                 int* __restrict__ cursor,
                                                 const float* __restrict__ dinv,
                                                 int* __restrict__ csr_col,
                                                 float* __restrict__ csr_norm, int E) {
  int i = blockIdx.x * 256 + threadIdx.x;
  if (i >= E) return;
  int r = row[i];
  int c = col[i];
  int p = atomicAdd(&cursor[r], 1);
  int o = offs[r] + p;
  csr_col[o] = c;
  csr_norm[o] = dinv[r] * dinv[c];
}

// ---------------- cast+transpose the 5 DxD weight matrices to bf16 ----------------
__global__ __launch_bounds__(256) void k_cast_w(const float* __restrict__ W0,
                                                const float* __restrict__ W1,
                                                const float* __restrict__ W2,
                                                const float* __restrict__ P0,
                                                const float* __restrict__ P1,
                                                unsigned short* __restrict__ Wt) {
  int idx = blockIdx.x * 256 + threadIdx.x; // 5*65536 total
  int m = idx >> 16;
  int e = idx & 65535;
  int k = e >> 8;
  int n = e & 255;
  const float* src = (m == 0) ? W0 : (m == 1) ? W1 : (m == 2) ? W2 : (m == 3) ? P0 : P1;
  Wt[(size_t)m * 65536 + (size_t)n * D + k] = f2bf(src[(size_t)k * D + n]);
}

// ---------------- emb fp32 -> bf16 (pad rows zeroed) ----------------
__global__ __launch_bounds__(256) void k_cast_emb(const float* __restrict__ emb,
                                                  unsigned short* __restrict__ XA, int N) {
  int idx = blockIdx.x * 256 + threadIdx.x; // one per 4 elements, covers Npad*64
  int i = idx >> 6;
  int c4 = (idx & 63) * 4;
  uint2 o;
  o.x = 0u;
  o.y = 0u;
  if (i < N) {
    float4 f = *(const float4*)(emb + (size_t)i * D + c4);
    o.x = (unsigned)f2bf(f.x) | ((unsigned)f2bf(f.y) << 16);
    o.y = (unsigned)f2bf(f.z) | ((unsigned)f2bf(f.w) << 16);
  }
  *(uint2*)(XA + (size_t)i * D + c4) = o;
}

// ---------------- GEMM: C[Npad,256] = A[Npad,256] @ W (Bt = W^T bf16) ----------------
// block 256 thr = 4 waves; block tile 64(M) x 64(N); wave: 16(M) x 64(N).
__global__ __launch_bounds__(256) void k_gemm(const unsigned short* __restrict__ A,
                                              const unsigned short* __restrict__ Bt,
                                              unsigned short* __restrict__ C) {
  int tid = threadIdx.x;
  int lane = tid & 63;
  int w = tid >> 6;
  int quad = lane >> 4;
  int l15 = lane & 15;
  int m0 = blockIdx.x * 64;
  int n0 = blockIdx.y * 64;
  int arow = m0 + w * 16 + l15;
  f32x4 acc[4] = {};
#pragma unroll
  for (int k0 = 0; k0 < 256; k0 += 32) {
    short8 a = *(const short8*)(A + (size_t)arow * D + k0 + quad * 8);
#pragma unroll
    for (int t = 0; t < 4; ++t) {
      short8 b = *(const short8*)(Bt + (size_t)(n0 + t * 16 + l15) * D + k0 + quad * 8);
      acc[t] = __builtin_amdgcn_mfma_f32_16x16x32_bf16(a, b, acc[t], 0, 0, 0);
    }
  }
  int crow = m0 + w * 16 + quad * 4;
#pragma unroll
  for (int t = 0; t < 4; ++t) {
#pragma unroll
    for (int r = 0; r < 4; ++r) {
      C[(size_t)(crow + r) * D + n0 + t * 16 + l15] = f2bf(acc[t][r]);
    }
  }
}

// ---------------- CSR aggregation: xout[r] = relu?( sum norm*h[c] + self + bias ) ----------------
// one wave per node; lane covers 4 consecutive columns.
__global__ __launch_bounds__(256) void k_agg(const unsigned short* __restrict__ h,
                                             const float* __restrict__ dinv,
                                             const int* __restrict__ offs,
                                             const int* __restrict__ csr_col,
                                             const float* __restrict__ csr_norm,
                                             const float* __restrict__ bias,
                                             unsigned short* __restrict__ xout,
                                             int do_relu) {
  int r = blockIdx.x * 4 + (threadIdx.x >> 6);
  int lane = threadIdx.x & 63;
  int c4 = lane * 4;
  float dr = dinv[r];
  float wself = dr * dr;
  uint2 s = *(const uint2*)(h + (size_t)r * D + c4);
  float a0 = wself * bf2f(s.x & 0xffffu);
  float a1 = wself * bf2f(s.x >> 16);
  float a2 = wself * bf2f(s.y & 0xffffu);
  float a3 = wself * bf2f(s.y >> 16);
  int e0 = offs[r], e1 = offs[r + 1];
  for (int e = e0; e < e1; ++e) {
    int c = csr_col[e];
    float wn = csr_norm[e];
    uint2 m = *(const uint2*)(h + (size_t)c * D + c4);
    a0 += wn * bf2f(m.x & 0xffffu);
    a1 += wn * bf2f(m.x >> 16);
    a2 += wn * bf2f(m.y & 0xffffu);
    a3 += wn * bf2f(m.y >> 16);
  }
  float4 bb = *(const float4*)(bias + c4);
  a0 += bb.x; a1 += bb.y; a2 += bb.z; a3 += bb.w;
  if (do_relu) {
    a0 = fmaxf(a0, 0.f); a1 = fmaxf(a1, 0.f);
    a2 = fmaxf(a2, 0.f); a3 = fmaxf(a3, 0.f);
  }
  uint2 o;
  o.x = (unsigned)f2bf(a0) | ((unsigned)f2bf(a1) << 16);
  o.y = (unsigned)f2bf(a2) | ((unsigned)f2bf(a3) << 16);
  *(uint2*)(xout + (size_t)r * D + c4) = o;
}

// ---------------- fused link predictor ----------------
// block = 256 thr = 4 waves; 64 queries per block; single LDS buffer ping-ponged
// through barriers (k-loop reads all of hA before epilogue overwrites it).
#define LPS 264  // LDS row stride in shorts: 528B = 33*16 (16B aligned), 132 dwords -> 4-bank shift/row
__global__ __launch_bounds__(256) void k_lp(const unsigned short* __restrict__ X,
                                            const int* __restrict__ eu,
                                            const int* __restrict__ ev,
                                            const unsigned short* __restrict__ P0t,
                                            const float* __restrict__ pb0,
                                            const unsigned short* __restrict__ P1t,
                                            const float* __restrict__ pb1,
                                            const float* __restrict__ P2,
                                            const float* __restrict__ pb2,
                                            float* __restrict__ out, int Q) {
  __shared__ unsigned short hA[64 * LPS];
  int tid = threadIdx.x;
  int lane = tid & 63;
  int w = tid >> 6;
  int quad = lane >> 4;
  int l15 = lane & 15;
  int q0 = blockIdx.x * 64;

  // stage h0 = x[u] * x[v] into hA (bf16)
  for (int qi = w; qi < 64; qi += 4) {
    int q = q0 + qi;
    uint2 o;
    o.x = 0u;
    o.y = 0u;
    if (q < Q) {
      int u = eu[q], v = ev[q];
      uint2 pu = *(const uint2*)(X + (size_t)u * D + lane * 4);
      uint2 pv = *(const uint2*)(X + (size_t)v * D + lane * 4);
      float p0 = bf2f(pu.x & 0xffffu) * bf2f(pv.x & 0xffffu);
      float p1 = bf2f(pu.x >> 16) * bf2f(pv.x >> 16);
      float p2 = bf2f(pu.y & 0xffffu) * bf2f(pv.y & 0xffffu);
      float p3 = bf2f(pu.y >> 16) * bf2f(pv.y >> 16);
      o.x = (unsigned)f2bf(p0) | ((unsigned)f2bf(p1) << 16);
      o.y = (unsigned)f2bf(p2) | ((unsigned)f2bf(p3) << 16);
    }
    *(uint2*)&hA[qi * LPS + lane * 4] = o;
  }
  __syncthreads();

  // two fused GEMM layers: hA <- relu(hA @ Pt + pb)
#pragma unroll 1
  for (int layer = 0; layer < 2; ++layer) {
    const unsigned short* Pt = (layer == 0) ? P0t : P1t;
    const float* pb = (layer == 0) ? pb0 : pb1;
    f32x4 acc[4][4] = {};
#pragma unroll
    for (int k0 = 0; k0 < 256; k0 += 32) {
      short8 a[4];
#pragma unroll
      for (int ms = 0; ms < 4; ++ms)
        a[ms] = *(const short8*)&hA[(ms * 16 + l15) * LPS + k0 + quad * 8];
#pragma unroll
      for (int ns = 0; ns < 4; ++ns) {
        short8 b = *(const short8*)(Pt + (size_t)(w * 64 + ns * 16 + l15) * D + k0 + quad * 8);
#pragma unroll
        for (int ms = 0; ms < 4; ++ms)
          acc[ms][ns] = __builtin_amdgcn_mfma_f32_16x16x32_bf16(a[ms], b, acc[ms][ns], 0, 0, 0);
      }
    }
    __syncthreads();  // all reads of hA complete before overwrite
#pragma unroll
    for (int ns = 0; ns < 4; ++ns) {
      int col = w * 64 + ns * 16 + l15;
      float bv = pb[col];
#pragma unroll
      for (int ms = 0; ms < 4; ++ms) {
        int rbase = ms * 16 + quad * 4;
#pragma unroll
        for (int r = 0; r < 4; ++r) {
          float vv = acc[ms][ns][r] + bv;
          vv = fmaxf(vv, 0.f);
          hA[(rbase + r) * LPS + col] = f2bf(vv);
        }
      }
    }
    __syncthreads();
  }

  // final dot with P2 + sigmoid; 4 threads per query
  int q = tid >> 2;
  int part = tid & 3;
  float s = 0.f;
  const unsigned short* hp = &hA[q * LPS + part * 64];
  const float* p2p = P2 + part * 64;
#pragma unroll 8
  for (int j = 0; j < 64; ++j) s += bf2f((unsigned int)hp[j]) * p2p[j];
  s += __shfl_xor(s, 1, 64);
  s += __shfl_xor(s, 2, 64);
  if (part == 0) {
    int qq = q0 + q;
    if (qq < Q) {
      float z = s + pb2[0];
      out[qq] = 1.f / (1.f + expf(-z));
    }
  }
}

extern "C" void kernel_launch(void* const* d_in, const int* in_sizes, int n_in,
                              void* d_out, int out_size, void* d_ws, size_t ws_size,
                              hipStream_t stream) {
  const int* adj_row = (const int*)d_in[0];
  const int* adj_col = (const int*)d_in[1];
  const int* edges = (const int*)d_in[2];
  const float* emb = (const float*)d_in[3];
  const float* W0 = (const float*)d_in[4];
  const float* b0 = (const float*)d_in[5];
  const float* W1 = (const float*)d_in[6];
  const float* b1 = (const float*)d_in[7];
  const float* W2 = (const float*)d_in[8];
  const float* b2 = (const float*)d_in[9];
  const float* P0 = (const float*)d_in[10];
  const float* pb0 = (const float*)d_in[11];
  const float* P1 = (const float*)d_in[12];
  const float* pb1 = (const float*)d_in[13];
  const float* P2 = (const float*)d_in[14];
  const float* pb2 = (const float*)d_in[15];
  float* out = (float*)d_out;

  int E = in_sizes[0];
  int Q = in_sizes[2] / 2;
  int N = in_sizes[3] / D;
  int Npad = ((N + 63) / 64) * 64;

  char* p = (char*)d_ws;
  auto alloc = [&](size_t bytes) {
    char* r = p;
    p += (bytes + 255) & ~(size_t)255;
    return r;
  };
  int* cnt = (int*)alloc((size_t)Npad * 4);
  int* cursor = (int*)alloc((size_t)Npad * 4);
  int* offs = (int*)alloc((size_t)(Npad + 1) * 4);
  float* dinv = (float*)alloc((size_t)Npad * 4);
  int* csr_col = (int*)alloc((size_t)E * 4);
  float* csr_norm = (float*)alloc((size_t)E * 4);
  unsigned short* Wt = (unsigned short*)alloc((size_t)5 * 65536 * 2);
  unsigned short* XA = (unsigned short*)alloc((size_t)Npad * D * 2);
  unsigned short* XC = (unsigned short*)alloc((size_t)Npad * D * 2);

  hipMemsetAsync(cnt, 0, (size_t)Npad * 4, stream);
  hipMemsetAsync(cursor, 0, (size_t)Npad * 4, stream);

  int eb = (E + 255) / 256;
  k_count<<<eb, 256, 0, stream>>>(adj_row, cnt, E);
  k_scan<<<1, 1024, 0, stream>>>(cnt, offs, dinv, Npad);
  k_scatter<<<eb, 256, 0, stream>>>(adj_row, adj_col, offs, cursor, dinv, csr_col, csr_norm, E);
  k_cast_w<<<5 * 65536 / 256, 256, 0, stream>>>(W0, W1, W2, P0, P1, Wt);
  k_cast_emb<<<Npad / 4, 256, 0, stream>>>(emb, XA, N);

  dim3 gg(Npad / 64, 4);
  const float* biases[3] = {b0, b1, b2};
  for (int l = 0; l < 3; ++l) {
    k_gemm<<<gg, 256, 0, stream>>>(XA, Wt + (size_t)l * 65536, XC);
    k_agg<<<Npad / 4, 256, 0, stream>>>(XC, dinv, offs, csr_col, csr_norm, biases[l], XA,
                                        (l < 2) ? 1 : 0);
  }
  k_lp<<<(Q + 63) / 64, 256, 0, stream>>>(XA, edges, edges + Q, Wt + (size_t)3 * 65536, pb0,
                                          Wt + (size_t)4 * 65536, pb1, P2, pb2, out, Q);
}

// Round 2
// 1363.093 us; speedup vs baseline: 1.3161x; 1.3161x over previous
//
#include <hip/hip_runtime.h>
#include <math.h>

#define D 256

typedef short short8 __attribute__((ext_vector_type(8)));
typedef float f32x4 __attribute__((ext_vector_type(4)));

__device__ __forceinline__ float bf2f(unsigned int h) {
  return __uint_as_float(h << 16);
}
__device__ __forceinline__ unsigned short f2bf(float f) {
  unsigned int u = __float_as_uint(f);
  u += 0x7fffu + ((u >> 16) & 1u);
  return (unsigned short)(u >> 16);
}
// product of two bf16x2-packed uints -> bf16x2-packed uint
__device__ __forceinline__ unsigned int bfmul2(unsigned int a, unsigned int b) {
  float lo = bf2f(a & 0xffffu) * bf2f(b & 0xffffu);
  float hi = bf2f(a >> 16) * bf2f(b >> 16);
  return (unsigned)f2bf(lo) | ((unsigned)f2bf(hi) << 16);
}

// ---------------- degree count ----------------
__global__ __launch_bounds__(256) void k_count(const int* __restrict__ row,
                                               int* __restrict__ cnt, int E) {
  int i = blockIdx.x * 256 + threadIdx.x;
  if (i < E) atomicAdd(&cnt[row[i]], 1);
}

// ---------------- 3-phase exclusive scan over Npad2 (multiple of 1024) ----------------
__global__ __launch_bounds__(256) void k_scan1(const int* __restrict__ cnt,
                                               int* __restrict__ bsum) {
  __shared__ int sw[4];
  int b = blockIdx.x, tid = threadIdx.x, lane = tid & 63, w = tid >> 6;
  int4 v = *(const int4*)(cnt + (size_t)b * 1024 + tid * 4);
  int s = v.x + v.y + v.z + v.w;
#pragma unroll
  for (int d = 32; d; d >>= 1) s += __shfl_xor(s, d, 64);
  if (lane == 0) sw[w] = s;
  __syncthreads();
  if (tid == 0) bsum[b] = sw[0] + sw[1] + sw[2] + sw[3];
}

__global__ __launch_bounds__(256) void k_scan2(int* __restrict__ bsum, int nb,
                                               int* __restrict__ offs_end) {
  __shared__ int sw[4];
  int tid = threadIdx.x, lane = tid & 63, w = tid >> 6;
  int v = (tid < nb) ? bsum[tid] : 0;
  int x = v;
#pragma unroll
  for (int d = 1; d < 64; d <<= 1) {
    int y = __shfl_up(x, d, 64);
    if (lane >= d) x += y;
  }
  if (lane == 63) sw[w] = x;
  __syncthreads();
  int woff = 0;
  for (int i = 0; i < w; ++i) woff += sw[i];
  int incl = woff + x;
  if (tid < nb) bsum[tid] = incl - v;  // exclusive block base
  if (tid == 0) *offs_end = sw[0] + sw[1] + sw[2] + sw[3];
}

__global__ __launch_bounds__(256) void k_scan3(const int* __restrict__ cnt,
                                               const int* __restrict__ bbase,
                                               int* __restrict__ offs,
                                               float* __restrict__ dinv) {
  __shared__ int sw[4];
  int b = blockIdx.x, tid = threadIdx.x, lane = tid & 63, w = tid >> 6;
  size_t base = (size_t)b * 1024 + tid * 4;
  int4 v = *(const int4*)(cnt + base);
  int s = v.x + v.y + v.z + v.w;
  int x = s;
#pragma unroll
  for (int d = 1; d < 64; d <<= 1) {
    int y = __shfl_up(x, d, 64);
    if (lane >= d) x += y;
  }
  if (lane == 63) sw[w] = x;
  __syncthreads();
  int woff = bbase[b];
  for (int i = 0; i < w; ++i) woff += sw[i];
  int excl = woff + x - s;
  int4 o;
  o.x = excl;
  o.y = excl + v.x;
  o.z = o.y + v.y;
  o.w = o.z + v.z;
  *(int4*)(offs + base) = o;
  float4 dv;
  dv.x = rsqrtf((float)(v.x + 1));
  dv.y = rsqrtf((float)(v.y + 1));
  dv.z = rsqrtf((float)(v.z + 1));
  dv.w = rsqrtf((float)(v.w + 1));
  *(float4*)(dinv + base) = dv;
}

// ---------------- CSR scatter + per-edge norm ----------------
__global__ __launch_bounds__(256) void k_scatter(const int* __restrict__ row,
                                                 const int* __restrict__ col,
                                                 const int* __restrict__ offs,
                                                 int* __restrict__ cursor,
                                                 const float* __restrict__ dinv,
                                                 int* __restrict__ csr_col,
                                                 float* __restrict__ csr_norm, int E) {
  int i = blockIdx.x * 256 + threadIdx.x;
  if (i >= E) return;
  int r = row[i];
  int c = col[i];
  int p = atomicAdd(&cursor[r], 1);
  int o = offs[r] + p;
  csr_col[o] = c;
  csr_norm[o] = dinv[r] * dinv[c];
}

// ---------------- cast+transpose the 5 DxD weight matrices to bf16 ----------------
__global__ __launch_bounds__(256) void k_cast_w(const float* __restrict__ W0,
                                                const float* __restrict__ W1,
                                                const float* __restrict__ W2,
                                                const float* __restrict__ P0,
                                                const float* __restrict__ P1,
                                                unsigned short* __restrict__ Wt) {
  int idx = blockIdx.x * 256 + threadIdx.x; // 5*65536 total
  int m = idx >> 16;
  int e = idx & 65535;
  int k = e >> 8;
  int n = e & 255;
  const float* src = (m == 0) ? W0 : (m == 1) ? W1 : (m == 2) ? W2 : (m == 3) ? P0 : P1;
  Wt[(size_t)m * 65536 + (size_t)n * D + k] = f2bf(src[(size_t)k * D + n]);
}

// ---------------- emb fp32 -> bf16 (pad rows zeroed) ----------------
__global__ __launch_bounds__(256) void k_cast_emb(const float* __restrict__ emb,
                                                  unsigned short* __restrict__ XA, int N) {
  int idx = blockIdx.x * 256 + threadIdx.x;
  int i = idx >> 6;
  int c4 = (idx & 63) * 4;
  uint2 o;
  o.x = 0u;
  o.y = 0u;
  if (i < N) {
    float4 f = *(const float4*)(emb + (size_t)i * D + c4);
    o.x = (unsigned)f2bf(f.x) | ((unsigned)f2bf(f.y) << 16);
    o.y = (unsigned)f2bf(f.z) | ((unsigned)f2bf(f.w) << 16);
  }
  *(uint2*)(XA + (size_t)i * D + c4) = o;
}

// ---------------- GEMM: C[Npad,256] = A[Npad,256] @ W (Bt = W^T bf16) ----------------
__global__ __launch_bounds__(256) void k_gemm(const unsigned short* __restrict__ A,
                                              const unsigned short* __restrict__ Bt,
                                              unsigned short* __restrict__ C) {
  int tid = threadIdx.x;
  int lane = tid & 63;
  int w = tid >> 6;
  int quad = lane >> 4;
  int l15 = lane & 15;
  int m0 = blockIdx.x * 64;
  int n0 = blockIdx.y * 64;
  int arow = m0 + w * 16 + l15;
  f32x4 acc[4] = {};
#pragma unroll
  for (int k0 = 0; k0 < 256; k0 += 32) {
    short8 a = *(const short8*)(A + (size_t)arow * D + k0 + quad * 8);
#pragma unroll
    for (int t = 0; t < 4; ++t) {
      short8 b = *(const short8*)(Bt + (size_t)(n0 + t * 16 + l15) * D + k0 + quad * 8);
      acc[t] = __builtin_amdgcn_mfma_f32_16x16x32_bf16(a, b, acc[t], 0, 0, 0);
    }
  }
  int crow = m0 + w * 16 + quad * 4;
#pragma unroll
  for (int t = 0; t < 4; ++t) {
#pragma unroll
    for (int r = 0; r < 4; ++r) {
      C[(size_t)(crow + r) * D + n0 + t * 16 + l15] = f2bf(acc[t][r]);
    }
  }
}

// ---------------- CSR aggregation, 8-wide software pipeline ----------------
__global__ __launch_bounds__(256) void k_agg(const unsigned short* __restrict__ h,
                                             const float* __restrict__ dinv,
                                             const int* __restrict__ offs,
                                             const int* __restrict__ csr_col,
                                             const float* __restrict__ csr_norm,
                                             const float* __restrict__ bias,
                                             unsigned short* __restrict__ xout,
                                             int do_relu) {
  int r = blockIdx.x * 4 + (threadIdx.x >> 6);
  int lane = threadIdx.x & 63;
  int c4 = lane * 4;
  float dr = dinv[r];
  float wself = dr * dr;
  uint2 s = *(const uint2*)(h + (size_t)r * D + c4);
  float a0 = wself * bf2f(s.x & 0xffffu);
  float a1 = wself * bf2f(s.x >> 16);
  float a2 = wself * bf2f(s.y & 0xffffu);
  float a3 = wself * bf2f(s.y >> 16);
  int e0 = offs[r], e1 = offs[r + 1];
  int e = e0;
  for (; e + 8 <= e1; e += 8) {
    int cc[8];
    float wn[8];
#pragma unroll
    for (int i = 0; i < 8; ++i) {
      cc[i] = csr_col[e + i];   // wave-uniform -> SMEM
      wn[i] = csr_norm[e + i];
    }
    uint2 mm[8];
#pragma unroll
    for (int i = 0; i < 8; ++i) mm[i] = *(const uint2*)(h + (size_t)cc[i] * D + c4);
#pragma unroll
    for (int i = 0; i < 8; ++i) {
      a0 += wn[i] * bf2f(mm[i].x & 0xffffu);
      a1 += wn[i] * bf2f(mm[i].x >> 16);
      a2 += wn[i] * bf2f(mm[i].y & 0xffffu);
      a3 += wn[i] * bf2f(mm[i].y >> 16);
    }
  }
  for (; e < e1; ++e) {
    int c = csr_col[e];
    float wn = csr_norm[e];
    uint2 m = *(const uint2*)(h + (size_t)c * D + c4);
    a0 += wn * bf2f(m.x & 0xffffu);
    a1 += wn * bf2f(m.x >> 16);
    a2 += wn * bf2f(m.y & 0xffffu);
    a3 += wn * bf2f(m.y >> 16);
  }
  float4 bb = *(const float4*)(bias + c4);
  a0 += bb.x; a1 += bb.y; a2 += bb.z; a3 += bb.w;
  if (do_relu) {
    a0 = fmaxf(a0, 0.f); a1 = fmaxf(a1, 0.f);
    a2 = fmaxf(a2, 0.f); a3 = fmaxf(a3, 0.f);
  }
  uint2 o;
  o.x = (unsigned)f2bf(a0) | ((unsigned)f2bf(a1) << 16);
  o.y = (unsigned)f2bf(a2) | ((unsigned)f2bf(a3) << 16);
  *(uint2*)(xout + (size_t)r * D + c4) = o;
}

// ---------------- fused link predictor ----------------
// block = 256 thr = 4 waves; 64 queries per block.
// gather: 4 threads per query, 16 independent 16B loads in flight.
// layer1 epilogue: P2 dot fused in registers (shfl reduce), no LDS writeback.
#define LPS 264
__global__ __launch_bounds__(256, 4) void k_lp(const unsigned short* __restrict__ X,
                                               const int* __restrict__ eu,
                                               const int* __restrict__ ev,
                                               const unsigned short* __restrict__ P0t,
                                               const float* __restrict__ pb0,
                                               const unsigned short* __restrict__ P1t,
                                               const float* __restrict__ pb1,
                                               const float* __restrict__ P2,
                                               const float* __restrict__ pb2,
                                               float* __restrict__ out, int Q) {
  __shared__ unsigned short hA[64 * LPS];
  __shared__ float sred[4][64];
  int tid = threadIdx.x;
  int lane = tid & 63;
  int w = tid >> 6;
  int quad = lane >> 4;
  int l15 = lane & 15;
  int q0 = blockIdx.x * 64;

  // ---- parallel gather: thread (qi, seg) covers shorts {c*32+seg*8 .. +8}, c=0..7
  {
    int qi = tid >> 2;
    int seg = tid & 3;
    int q = q0 + qi;
    int u = 0, v = 0;
    if (q < Q) { u = eu[q]; v = ev[q]; }
    const unsigned short* pu = X + (size_t)u * D;
    const unsigned short* pv = X + (size_t)v * D;
    uint4 ru[8], rv[8];
#pragma unroll
    for (int c = 0; c < 8; ++c) {
      int off = c * 32 + seg * 8;
      ru[c] = *(const uint4*)(pu + off);
      rv[c] = *(const uint4*)(pv + off);
    }
#pragma unroll
    for (int c = 0; c < 8; ++c) {
      int off = c * 32 + seg * 8;
      uint4 o;
      o.x = bfmul2(ru[c].x, rv[c].x);
      o.y = bfmul2(ru[c].y, rv[c].y);
      o.z = bfmul2(ru[c].z, rv[c].z);
      o.w = bfmul2(ru[c].w, rv[c].w);
      if (q >= Q) { o.x = 0u; o.y = 0u; o.z = 0u; o.w = 0u; }
      *(uint4*)&hA[qi * LPS + off] = o;
    }
  }
  __syncthreads();

  // ---- layer 0: hA <- relu(hA @ P0t + pb0)
  {
    f32x4 acc[4][4] = {};
#pragma unroll
    for (int k0 = 0; k0 < 256; k0 += 32) {
      short8 a[4];
#pragma unroll
      for (int ms = 0; ms < 4; ++ms)
        a[ms] = *(const short8*)&hA[(ms * 16 + l15) * LPS + k0 + quad * 8];
#pragma unroll
      for (int ns = 0; ns < 4; ++ns) {
        short8 b = *(const short8*)(P0t + (size_t)(w * 64 + ns * 16 + l15) * D + k0 + quad * 8);
#pragma unroll
        for (int ms = 0; ms < 4; ++ms)
          acc[ms][ns] = __builtin_amdgcn_mfma_f32_16x16x32_bf16(a[ms], b, acc[ms][ns], 0, 0, 0);
      }
    }
    __syncthreads();
#pragma unroll
    for (int ns = 0; ns < 4; ++ns) {
      int col = w * 64 + ns * 16 + l15;
      float bv = pb0[col];
#pragma unroll
      for (int ms = 0; ms < 4; ++ms) {
        int rbase = ms * 16 + quad * 4;
#pragma unroll
        for (int r = 0; r < 4; ++r) {
          float vv = fmaxf(acc[ms][ns][r] + bv, 0.f);
          hA[(rbase + r) * LPS + col] = f2bf(vv);
        }
      }
    }
    __syncthreads();
  }

  // ---- layer 1 + fused P2 dot + sigmoid
  {
    f32x4 acc[4][4] = {};
#pragma unroll
    for (int k0 = 0; k0 < 256; k0 += 32) {
      short8 a[4];
#pragma unroll
      for (int ms = 0; ms < 4; ++ms)
        a[ms] = *(const short8*)&hA[(ms * 16 + l15) * LPS + k0 + quad * 8];
#pragma unroll
      for (int ns = 0; ns < 4; ++ns) {
        short8 b = *(const short8*)(P1t + (size_t)(w * 64 + ns * 16 + l15) * D + k0 + quad * 8);
#pragma unroll
        for (int ms = 0; ms < 4; ++ms)
          acc[ms][ns] = __builtin_amdgcn_mfma_f32_16x16x32_bf16(a[ms], b, acc[ms][ns], 0, 0, 0);
      }
    }
    float p2v[4], pbv[4];
#pragma unroll
    for (int ns = 0; ns < 4; ++ns) {
      int col = w * 64 + ns * 16 + l15;
      p2v[ns] = P2[col];
      pbv[ns] = pb1[col];
    }
    float part[16];
#pragma unroll
    for (int ms = 0; ms < 4; ++ms)
#pragma unroll
      for (int r = 0; r < 4; ++r) {
        float s = 0.f;
#pragma unroll
        for (int ns = 0; ns < 4; ++ns)
          s += fmaxf(acc[ms][ns][r] + pbv[ns], 0.f) * p2v[ns];
        part[ms * 4 + r] = s;
      }
#pragma unroll
    for (int d = 1; d < 16; d <<= 1)
#pragma unroll
      for (int i = 0; i < 16; ++i) part[i] += __shfl_xor(part[i], d, 64);
    if (l15 == 0) {
#pragma unroll
      for (int i = 0; i < 16; ++i) {
        int ms = i >> 2, r = i & 3;
        sred[w][ms * 16 + quad * 4 + r] = part[i];
      }
    }
    __syncthreads();
    if (tid < 64) {
      float s = sred[0][tid] + sred[1][tid] + sred[2][tid] + sred[3][tid] + pb2[0];
      int qq = q0 + tid;
      if (qq < Q) out[qq] = 1.f / (1.f + expf(-s));
    }
  }
}

extern "C" void kernel_launch(void* const* d_in, const int* in_sizes, int n_in,
                              void* d_out, int out_size, void* d_ws, size_t ws_size,
                              hipStream_t stream) {
  const int* adj_row = (const int*)d_in[0];
  const int* adj_col = (const int*)d_in[1];
  const int* edges = (const int*)d_in[2];
  const float* emb = (const float*)d_in[3];
  const float* W0 = (const float*)d_in[4];
  const float* b0 = (const float*)d_in[5];
  const float* W1 = (const float*)d_in[6];
  const float* b1 = (const float*)d_in[7];
  const float* W2 = (const float*)d_in[8];
  const float* b2 = (const float*)d_in[9];
  const float* P0 = (const float*)d_in[10];
  const float* pb0 = (const float*)d_in[11];
  const float* P1 = (const float*)d_in[12];
  const float* pb1 = (const float*)d_in[13];
  const float* P2 = (const float*)d_in[14];
  const float* pb2 = (const float*)d_in[15];
  float* out = (float*)d_out;

  int E = in_sizes[0];
  int Q = in_sizes[2] / 2;
  int N = in_sizes[3] / D;
  int Npad = ((N + 63) / 64) * 64;
  int Npad2 = ((N + 1023) / 1024) * 1024;
  int nb = Npad2 / 1024;

  char* p = (char*)d_ws;
  auto alloc = [&](size_t bytes) {
    char* r = p;
    p += (bytes + 255) & ~(size_t)255;
    return r;
  };
  int* cnt = (int*)alloc((size_t)Npad2 * 4);
  int* cursor = (int*)alloc((size_t)Npad2 * 4);
  int* offs = (int*)alloc((size_t)(Npad2 + 1) * 4);
  float* dinv = (float*)alloc((size_t)Npad2 * 4);
  int* bsum = (int*)alloc((size_t)nb * 4);
  int* csr_col = (int*)alloc((size_t)E * 4);
  float* csr_norm = (float*)alloc((size_t)E * 4);
  unsigned short* Wt = (unsigned short*)alloc((size_t)5 * 65536 * 2);
  unsigned short* XA = (unsigned short*)alloc((size_t)Npad * D * 2);
  unsigned short* XC = (unsigned short*)alloc((size_t)Npad * D * 2);

  hipMemsetAsync(cnt, 0, (size_t)Npad2 * 4, stream);
  hipMemsetAsync(cursor, 0, (size_t)Npad2 * 4, stream);

  int eb = (E + 255) / 256;
  k_count<<<eb, 256, 0, stream>>>(adj_row, cnt, E);
  k_scan1<<<nb, 256, 0, stream>>>(cnt, bsum);
  k_scan2<<<1, 256, 0, stream>>>(bsum, nb, offs + Npad2);
  k_scan3<<<nb, 256, 0, stream>>>(cnt, bsum, offs, dinv);
  k_scatter<<<eb, 256, 0, stream>>>(adj_row, adj_col, offs, cursor, dinv, csr_col, csr_norm, E);
  k_cast_w<<<5 * 65536 / 256, 256, 0, stream>>>(W0, W1, W2, P0, P1, Wt);
  k_cast_emb<<<Npad / 4, 256, 0, stream>>>(emb, XA, N);

  dim3 gg(Npad / 64, 4);
  const float* biases[3] = {b0, b1, b2};
  for (int l = 0; l < 3; ++l) {
    k_gemm<<<gg, 256, 0, stream>>>(XA, Wt + (size_t)l * 65536, XC);
    k_agg<<<Npad / 4, 256, 0, stream>>>(XC, dinv, offs, csr_col, csr_norm, biases[l], XA,
                                        (l < 2) ? 1 : 0);
  }
  k_lp<<<(Q + 63) / 64, 256, 0, stream>>>(XA, edges, edges + Q, Wt + (size_t)3 * 65536, pb0,
                                          Wt + (size_t)4 * 65536, pb1, P2, pb2, out, Q);
}

// Round 3
// 1196.464 us; speedup vs baseline: 1.4993x; 1.1393x over previous
//
#include <hip/hip_runtime.h>
#include <math.h>

#define D 256

typedef short short8 __attribute__((ext_vector_type(8)));
typedef float f32x4 __attribute__((ext_vector_type(4)));
typedef float f32x2 __attribute__((ext_vector_type(2)));

__device__ __forceinline__ float bf2f(unsigned int h) {
  return __uint_as_float(h << 16);
}
__device__ __forceinline__ unsigned short f2bf(float f) {
  unsigned int u = __float_as_uint(f);
  u += 0x7fffu + ((u >> 16) & 1u);
  return (unsigned short)(u >> 16);
}
// truncating bf16x2 pack (error <=1ulp, fine at our error budget)
__device__ __forceinline__ unsigned int packtrunc(float a, float b) {
  return (__float_as_uint(a) >> 16) | (__float_as_uint(b) & 0xffff0000u);
}
__device__ __forceinline__ unsigned int pk_fp8x4(float a, float b, float c, float d) {
  unsigned int r = 0;
  r = __builtin_amdgcn_cvt_pk_fp8_f32(a, b, r, false);
  r = __builtin_amdgcn_cvt_pk_fp8_f32(c, d, r, true);
  return r;
}
__device__ __forceinline__ void up_fp8x4(unsigned int x, float& a, float& b, float& c,
                                         float& d) {
  f32x2 lo = __builtin_amdgcn_cvt_pk_f32_fp8(x, false);
  f32x2 hi = __builtin_amdgcn_cvt_pk_f32_fp8(x, true);
  a = lo.x; b = lo.y; c = hi.x; d = hi.y;
}

// ---------------- degree count ----------------
__global__ __launch_bounds__(256) void k_count(const int* __restrict__ row,
                                               int* __restrict__ cnt, int E) {
  int i = blockIdx.x * 256 + threadIdx.x;
  if (i < E) atomicAdd(&cnt[row[i]], 1);
}

// ---------------- 3-phase exclusive scan over Npad2 (multiple of 1024) ----------------
__global__ __launch_bounds__(256) void k_scan1(const int* __restrict__ cnt,
                                               int* __restrict__ bsum) {
  __shared__ int sw[4];
  int b = blockIdx.x, tid = threadIdx.x, lane = tid & 63, w = tid >> 6;
  int4 v = *(const int4*)(cnt + (size_t)b * 1024 + tid * 4);
  int s = v.x + v.y + v.z + v.w;
#pragma unroll
  for (int d = 32; d; d >>= 1) s += __shfl_xor(s, d, 64);
  if (lane == 0) sw[w] = s;
  __syncthreads();
  if (tid == 0) bsum[b] = sw[0] + sw[1] + sw[2] + sw[3];
}

__global__ __launch_bounds__(256) void k_scan2(int* __restrict__ bsum, int nb,
                                               int* __restrict__ offs_end) {
  __shared__ int sw[4];
  int tid = threadIdx.x, lane = tid & 63, w = tid >> 6;
  int v = (tid < nb) ? bsum[tid] : 0;
  int x = v;
#pragma unroll
  for (int d = 1; d < 64; d <<= 1) {
    int y = __shfl_up(x, d, 64);
    if (lane >= d) x += y;
  }
  if (lane == 63) sw[w] = x;
  __syncthreads();
  int woff = 0;
  for (int i = 0; i < w; ++i) woff += sw[i];
  int incl = woff + x;
  if (tid < nb) bsum[tid] = incl - v;
  if (tid == 0) *offs_end = sw[0] + sw[1] + sw[2] + sw[3];
}

__global__ __launch_bounds__(256) void k_scan3(const int* __restrict__ cnt,
                                               const int* __restrict__ bbase,
                                               int* __restrict__ offs,
                                               float* __restrict__ dinv) {
  __shared__ int sw[4];
  int b = blockIdx.x, tid = threadIdx.x, lane = tid & 63, w = tid >> 6;
  size_t base = (size_t)b * 1024 + tid * 4;
  int4 v = *(const int4*)(cnt + base);
  int s = v.x + v.y + v.z + v.w;
  int x = s;
#pragma unroll
  for (int d = 1; d < 64; d <<= 1) {
    int y = __shfl_up(x, d, 64);
    if (lane >= d) x += y;
  }
  if (lane == 63) sw[w] = x;
  __syncthreads();
  int woff = bbase[b];
  for (int i = 0; i < w; ++i) woff += sw[i];
  int excl = woff + x - s;
  int4 o;
  o.x = excl;
  o.y = excl + v.x;
  o.z = o.y + v.y;
  o.w = o.z + v.z;
  *(int4*)(offs + base) = o;
  float4 dv;
  dv.x = rsqrtf((float)(v.x + 1));
  dv.y = rsqrtf((float)(v.y + 1));
  dv.z = rsqrtf((float)(v.z + 1));
  dv.w = rsqrtf((float)(v.w + 1));
  *(float4*)(dinv + base) = dv;
}

// ---------------- CSR scatter + per-edge (col, norm) packed int2 ----------------
__global__ __launch_bounds__(256) void k_scatter(const int* __restrict__ row,
                                                 const int* __restrict__ col,
                                                 const int* __restrict__ offs,
                                                 int* __restrict__ cursor,
                                                 const float* __restrict__ dinv,
                                                 int2* __restrict__ csr, int E) {
  int i = blockIdx.x * 256 + threadIdx.x;
  if (i >= E) return;
  int r = row[i];
  int c = col[i];
  int p = atomicAdd(&cursor[r], 1);
  int o = offs[r] + p;
  int2 cn;
  cn.x = c;
  cn.y = __float_as_int(dinv[r] * dinv[c]);
  csr[o] = cn;
}

// ---------------- cast+transpose the 5 DxD weight matrices to bf16 ----------------
__global__ __launch_bounds__(256) void k_cast_w(const float* __restrict__ W0,
                                                const float* __restrict__ W1,
                                                const float* __restrict__ W2,
                                                const float* __restrict__ P0,
                                                const float* __restrict__ P1,
                                                unsigned short* __restrict__ Wt) {
  int idx = blockIdx.x * 256 + threadIdx.x;
  int m = idx >> 16;
  int e = idx & 65535;
  int k = e >> 8;
  int n = e & 255;
  const float* src = (m == 0) ? W0 : (m == 1) ? W1 : (m == 2) ? W2 : (m == 3) ? P0 : P1;
  Wt[(size_t)m * 65536 + (size_t)n * D + k] = f2bf(src[(size_t)k * D + n]);
}

// ---------------- emb fp32 -> bf16 (pad rows zeroed) ----------------
__global__ __launch_bounds__(256) void k_cast_emb(const float* __restrict__ emb,
                                                  unsigned short* __restrict__ XA, int N) {
  int idx = blockIdx.x * 256 + threadIdx.x;
  int i = idx >> 6;
  int c4 = (idx & 63) * 4;
  uint2 o;
  o.x = 0u;
  o.y = 0u;
  if (i < N) {
    float4 f = *(const float4*)(emb + (size_t)i * D + c4);
    o.x = (unsigned)f2bf(f.x) | ((unsigned)f2bf(f.y) << 16);
    o.y = (unsigned)f2bf(f.z) | ((unsigned)f2bf(f.w) << 16);
  }
  *(uint2*)(XA + (size_t)i * D + c4) = o;
}

// ---------------- GEMM: H8[Npad,256](fp8) = A[Npad,256](bf16) @ W ----------------
// block 256 thr = 4 waves; block tile 64(M) x 256(N full); A read once.
// epilogue: acc -> LDS bf16 tile -> coalesced fp8 pack+store.
#define TLS 264
__global__ __launch_bounds__(256) void k_gemm(const unsigned short* __restrict__ A,
                                              const unsigned short* __restrict__ Bt,
                                              unsigned int* __restrict__ C8) {
  __shared__ unsigned short tile[64 * TLS];
  int tid = threadIdx.x;
  int lane = tid & 63;
  int w = tid >> 6;
  int quad = lane >> 4;
  int l15 = lane & 15;
  int m0 = blockIdx.x * 64;
  int arow = m0 + w * 16 + l15;
  f32x4 acc[16] = {};
#pragma unroll 2
  for (int k0 = 0; k0 < 256; k0 += 32) {
    short8 a = *(const short8*)(A + (size_t)arow * D + k0 + quad * 8);
#pragma unroll
    for (int t = 0; t < 16; ++t) {
      short8 b = *(const short8*)(Bt + (size_t)(t * 16 + l15) * D + k0 + quad * 8);
      acc[t] = __builtin_amdgcn_mfma_f32_16x16x32_bf16(a, b, acc[t], 0, 0, 0);
    }
  }
  int trow = w * 16 + quad * 4;
#pragma unroll
  for (int t = 0; t < 16; ++t)
#pragma unroll
    for (int r = 0; r < 4; ++r)
      tile[(trow + r) * TLS + t * 16 + l15] = f2bf(acc[t][r]);
  __syncthreads();
  int row = tid >> 2;
  int seg = tid & 3;
  const unsigned short* src = &tile[row * TLS + seg * 64];
  unsigned int* dst = C8 + (((size_t)(m0 + row) * D + seg * 64) >> 2);
#pragma unroll
  for (int k = 0; k < 4; ++k) {
    short8 x0 = *(const short8*)(src + k * 16);
    short8 x1 = *(const short8*)(src + k * 16 + 8);
    uint4 o;
    o.x = pk_fp8x4(bf2f((unsigned short)x0[0]), bf2f((unsigned short)x0[1]),
                   bf2f((unsigned short)x0[2]), bf2f((unsigned short)x0[3]));
    o.y = pk_fp8x4(bf2f((unsigned short)x0[4]), bf2f((unsigned short)x0[5]),
                   bf2f((unsigned short)x0[6]), bf2f((unsigned short)x0[7]));
    o.z = pk_fp8x4(bf2f((unsigned short)x1[0]), bf2f((unsigned short)x1[1]),
                   bf2f((unsigned short)x1[2]), bf2f((unsigned short)x1[3]));
    o.w = pk_fp8x4(bf2f((unsigned short)x1[4]), bf2f((unsigned short)x1[5]),
                   bf2f((unsigned short)x1[6]), bf2f((unsigned short)x1[7]));
    *(uint4*)(dst + k * 4) = o;
  }
}

// ---------------- CSR aggregation over fp8 h; 1 dword/lane/edge, batched-8 ----------------
// mode 0: relu + bf16 out (layers 0,1). mode 1: linear + fp8 out (layer 2).
__global__ __launch_bounds__(256) void k_agg(const unsigned int* __restrict__ h8,
                                             const float* __restrict__ dinv,
                                             const int* __restrict__ offs,
                                             const int2* __restrict__ csr,
                                             const float* __restrict__ bias,
                                             unsigned short* __restrict__ xb,
                                             unsigned int* __restrict__ x8, int mode) {
  int r = blockIdx.x * 4 + (threadIdx.x >> 6);
  int lane = threadIdx.x & 63;
  float dr = dinv[r];
  float wself = dr * dr;
  unsigned int sv = h8[(size_t)r * 64 + lane];
  float a0, a1, a2, a3;
  up_fp8x4(sv, a0, a1, a2, a3);
  a0 *= wself; a1 *= wself; a2 *= wself; a3 *= wself;
  int e0 = offs[r], e1 = offs[r + 1];
  for (int e = e0; e < e1; e += 8) {
    int cc[8];
    float wn[8];
#pragma unroll
    for (int i = 0; i < 8; ++i) {
      bool valid = (e + i) < e1;
      int2 cn = csr[valid ? (e + i) : e0];
      cc[i] = valid ? cn.x : 0;
      wn[i] = valid ? __int_as_float(cn.y) : 0.f;
    }
    unsigned int mm[8];
#pragma unroll
    for (int i = 0; i < 8; ++i) mm[i] = h8[(size_t)cc[i] * 64 + lane];
#pragma unroll
    for (int i = 0; i < 8; ++i) {
      float b0, b1, b2, b3;
      up_fp8x4(mm[i], b0, b1, b2, b3);
      a0 += wn[i] * b0;
      a1 += wn[i] * b1;
      a2 += wn[i] * b2;
      a3 += wn[i] * b3;
    }
  }
  float4 bb = *(const float4*)(bias + lane * 4);
  a0 += bb.x; a1 += bb.y; a2 += bb.z; a3 += bb.w;
  if (mode == 0) {
    a0 = fmaxf(a0, 0.f); a1 = fmaxf(a1, 0.f);
    a2 = fmaxf(a2, 0.f); a3 = fmaxf(a3, 0.f);
    uint2 o;
    o.x = (unsigned)f2bf(a0) | ((unsigned)f2bf(a1) << 16);
    o.y = (unsigned)f2bf(a2) | ((unsigned)f2bf(a3) << 16);
    *(uint2*)(xb + (size_t)r * D + lane * 4) = o;
  } else {
    x8[(size_t)r * 64 + lane] = pk_fp8x4(a0, a1, a2, a3);
  }
}

// ---------------- fused link predictor (fp8 gather) ----------------
#define LPS 264
__global__ __launch_bounds__(256, 4) void k_lp(const unsigned char* __restrict__ X8,
                                               const int* __restrict__ eu,
                                               const int* __restrict__ ev,
                                               const unsigned short* __restrict__ P0t,
                                               const float* __restrict__ pb0,
                                               const unsigned short* __restrict__ P1t,
                                               const float* __restrict__ pb1,
                                               const float* __restrict__ P2,
                                               const float* __restrict__ pb2,
                                               float* __restrict__ out, int Q) {
  __shared__ unsigned short hA[64 * LPS];
  __shared__ float sred[4][64];
  int tid = threadIdx.x;
  int lane = tid & 63;
  int w = tid >> 6;
  int quad = lane >> 4;
  int l15 = lane & 15;
  int q0 = blockIdx.x * 64;

  // ---- gather: 4 threads per query; fp8 rows (256 B); 8 x 16B loads in flight
  {
    int qi = tid >> 2;
    int seg = tid & 3;
    int q = q0 + qi;
    int u = 0, v = 0;
    if (q < Q) { u = eu[q]; v = ev[q]; }
    const uint4* pu = (const uint4*)(X8 + (size_t)u * 256 + seg * 64);
    const uint4* pv = (const uint4*)(X8 + (size_t)v * 256 + seg * 64);
    uint4 ru[4], rv[4];
#pragma unroll
    for (int c = 0; c < 4; ++c) { ru[c] = pu[c]; rv[c] = pv[c]; }
#pragma unroll
    for (int c = 0; c < 4; ++c) {
      float uf[16], vf[16];
      up_fp8x4(ru[c].x, uf[0], uf[1], uf[2], uf[3]);
      up_fp8x4(ru[c].y, uf[4], uf[5], uf[6], uf[7]);
      up_fp8x4(ru[c].z, uf[8], uf[9], uf[10], uf[11]);
      up_fp8x4(ru[c].w, uf[12], uf[13], uf[14], uf[15]);
      up_fp8x4(rv[c].x, vf[0], vf[1], vf[2], vf[3]);
      up_fp8x4(rv[c].y, vf[4], vf[5], vf[6], vf[7]);
      up_fp8x4(rv[c].z, vf[8], vf[9], vf[10], vf[11]);
      up_fp8x4(rv[c].w, vf[12], vf[13], vf[14], vf[15]);
      uint4 o0, o1;
      if (q < Q) {
        o0.x = packtrunc(uf[0] * vf[0], uf[1] * vf[1]);
        o0.y = packtrunc(uf[2] * vf[2], uf[3] * vf[3]);
        o0.z = packtrunc(uf[4] * vf[4], uf[5] * vf[5]);
        o0.w = packtrunc(uf[6] * vf[6], uf[7] * vf[7]);
        o1.x = packtrunc(uf[8] * vf[8], uf[9] * vf[9]);
        o1.y = packtrunc(uf[10] * vf[10], uf[11] * vf[11]);
        o1.z = packtrunc(uf[12] * vf[12], uf[13] * vf[13]);
        o1.w = packtrunc(uf[14] * vf[14], uf[15] * vf[15]);
      } else {
        o0.x = o0.y = o0.z = o0.w = 0u;
        o1.x = o1.y = o1.z = o1.w = 0u;
      }
      int off = seg * 64 + c * 16;
      *(uint4*)&hA[qi * LPS + off] = o0;
      *(uint4*)&hA[qi * LPS + off + 8] = o1;
    }
  }
  __syncthreads();

  // ---- layer 0: hA <- relu(hA @ P0t + pb0)
  {
    f32x4 acc[4][4] = {};
#pragma unroll
    for (int k0 = 0; k0 < 256; k0 += 32) {
      short8 a[4];
#pragma unroll
      for (int ms = 0; ms < 4; ++ms)
        a[ms] = *(const short8*)&hA[(ms * 16 + l15) * LPS + k0 + quad * 8];
#pragma unroll
      for (int ns = 0; ns < 4; ++ns) {
        short8 b = *(const short8*)(P0t + (size_t)(w * 64 + ns * 16 + l15) * D + k0 + quad * 8);
#pragma unroll
        for (int ms = 0; ms < 4; ++ms)
          acc[ms][ns] = __builtin_amdgcn_mfma_f32_16x16x32_bf16(a[ms], b, acc[ms][ns], 0, 0, 0);
      }
    }
    __syncthreads();
#pragma unroll
    for (int ns = 0; ns < 4; ++ns) {
      int col = w * 64 + ns * 16 + l15;
      float bv = pb0[col];
#pragma unroll
      for (int ms = 0; ms < 4; ++ms) {
        int rbase = ms * 16 + quad * 4;
#pragma unroll
        for (int r = 0; r < 4; ++r) {
          float vv = fmaxf(acc[ms][ns][r] + bv, 0.f);
          hA[(rbase + r) * LPS + col] = f2bf(vv);
        }
      }
    }
    __syncthreads();
  }

  // ---- layer 1 + fused P2 dot + sigmoid
  {
    f32x4 acc[4][4] = {};
#pragma unroll
    for (int k0 = 0; k0 < 256; k0 += 32) {
      short8 a[4];
#pragma unroll
      for (int ms = 0; ms < 4; ++ms)
        a[ms] = *(const short8*)&hA[(ms * 16 + l15) * LPS + k0 + quad * 8];
#pragma unroll
      for (int ns = 0; ns < 4; ++ns) {
        short8 b = *(const short8*)(P1t + (size_t)(w * 64 + ns * 16 + l15) * D + k0 + quad * 8);
#pragma unroll
        for (int ms = 0; ms < 4; ++ms)
          acc[ms][ns] = __builtin_amdgcn_mfma_f32_16x16x32_bf16(a[ms], b, acc[ms][ns], 0, 0, 0);
      }
    }
    float p2v[4], pbv[4];
#pragma unroll
    for (int ns = 0; ns < 4; ++ns) {
      int col = w * 64 + ns * 16 + l15;
      p2v[ns] = P2[col];
      pbv[ns] = pb1[col];
    }
    float part[16];
#pragma unroll
    for (int ms = 0; ms < 4; ++ms)
#pragma unroll
      for (int r = 0; r < 4; ++r) {
        float s = 0.f;
#pragma unroll
        for (int ns = 0; ns < 4; ++ns)
          s += fmaxf(acc[ms][ns][r] + pbv[ns], 0.f) * p2v[ns];
        part[ms * 4 + r] = s;
      }
#pragma unroll
    for (int d = 1; d < 16; d <<= 1)
#pragma unroll
      for (int i = 0; i < 16; ++i) part[i] += __shfl_xor(part[i], d, 64);
    if (l15 == 0) {
#pragma unroll
      for (int i = 0; i < 16; ++i) {
        int ms = i >> 2, r = i & 3;
        sred[w][ms * 16 + quad * 4 + r] = part[i];
      }
    }
    __syncthreads();
    if (tid < 64) {
      float s = sred[0][tid] + sred[1][tid] + sred[2][tid] + sred[3][tid] + pb2[0];
      int qq = q0 + tid;
      if (qq < Q) out[qq] = 1.f / (1.f + expf(-s));
    }
  }
}

extern "C" void kernel_launch(void* const* d_in, const int* in_sizes, int n_in,
                              void* d_out, int out_size, void* d_ws, size_t ws_size,
                              hipStream_t stream) {
  const int* adj_row = (const int*)d_in[0];
  const int* adj_col = (const int*)d_in[1];
  const int* edges = (const int*)d_in[2];
  const float* emb = (const float*)d_in[3];
  const float* W0 = (const float*)d_in[4];
  const float* b0 = (const float*)d_in[5];
  const float* W1 = (const float*)d_in[6];
  const float* b1 = (const float*)d_in[7];
  const float* W2 = (const float*)d_in[8];
  const float* b2 = (const float*)d_in[9];
  const float* P0 = (const float*)d_in[10];
  const float* pb0 = (const float*)d_in[11];
  const float* P1 = (const float*)d_in[12];
  const float* pb1 = (const float*)d_in[13];
  const float* P2 = (const float*)d_in[14];
  const float* pb2 = (const float*)d_in[15];
  float* out = (float*)d_out;

  int E = in_sizes[0];
  int Q = in_sizes[2] / 2;
  int N = in_sizes[3] / D;
  int Npad = ((N + 63) / 64) * 64;
  int Npad2 = ((N + 1023) / 1024) * 1024;
  int nb = Npad2 / 1024;

  char* p = (char*)d_ws;
  auto alloc = [&](size_t bytes) {
    char* r = p;
    p += (bytes + 255) & ~(size_t)255;
    return r;
  };
  int* cnt = (int*)alloc((size_t)Npad2 * 4);
  int* cursor = (int*)alloc((size_t)Npad2 * 4);
  int* offs = (int*)alloc((size_t)(Npad2 + 1) * 4);
  float* dinv = (float*)alloc((size_t)Npad2 * 4);
  int* bsum = (int*)alloc((size_t)nb * 4);
  int2* csr = (int2*)alloc((size_t)E * 8);
  unsigned short* Wt = (unsigned short*)alloc((size_t)5 * 65536 * 2);
  unsigned short* XA = (unsigned short*)alloc((size_t)Npad * D * 2);
  unsigned int* XC8 = (unsigned int*)alloc((size_t)Npad * D);
  unsigned int* XA8 = (unsigned int*)XA;  // alias: XA(bf16) dead when layer-2 agg writes fp8

  hipMemsetAsync(cnt, 0, (size_t)Npad2 * 4, stream);
  hipMemsetAsync(cursor, 0, (size_t)Npad2 * 4, stream);

  int eb = (E + 255) / 256;
  k_count<<<eb, 256, 0, stream>>>(adj_row, cnt, E);
  k_scan1<<<nb, 256, 0, stream>>>(cnt, bsum);
  k_scan2<<<1, 256, 0, stream>>>(bsum, nb, offs + Npad2);
  k_scan3<<<nb, 256, 0, stream>>>(cnt, bsum, offs, dinv);
  k_scatter<<<eb, 256, 0, stream>>>(adj_row, adj_col, offs, cursor, dinv, csr, E);
  k_cast_w<<<5 * 65536 / 256, 256, 0, stream>>>(W0, W1, W2, P0, P1, Wt);
  k_cast_emb<<<Npad / 4, 256, 0, stream>>>(emb, XA, N);

  const float* biases[3] = {b0, b1, b2};
  for (int l = 0; l < 3; ++l) {
    k_gemm<<<Npad / 64, 256, 0, stream>>>(XA, Wt + (size_t)l * 65536, XC8);
    k_agg<<<Npad / 4, 256, 0, stream>>>(XC8, dinv, offs, csr, biases[l], XA, XA8,
                                        (l < 2) ? 0 : 1);
  }
  k_lp<<<(Q + 63) / 64, 256, 0, stream>>>((const unsigned char*)XA8, edges, edges + Q,
                                          Wt + (size_t)3 * 65536, pb0,
                                          Wt + (size_t)4 * 65536, pb1, P2, pb2, out, Q);
}